// Round 13
// baseline (254.334 us; speedup 1.0000x reference)
//
#include <hip/hip_runtime.h>
#include <math.h>

#define BB 16384      // B
#define CC 50         // clusters
#define KK 128        // top-K
#define DD 128        // feature dim
#define MM 12800      // CC*2*KK rows of F
#define NBLK 100      // 128-row blocks of F
#define NCHUNK 13     // J-chunks per row (chunk = 8 tiles)
#define CHT 8         // tiles per chunk
#define MAXCAND 2048
#define TCAND 0.97f
#define NPART 64      // candidate partitions (256 rows each)
#define RPP 256       // rows per partition
#define PCAP 32       // per (partition,cluster) capacity; expected ~7.7
#define SIMGRID (NBLK * NCHUNK + 2 * CC)   // 1400
// F rows pre-scaled by SQS = sqrt(2/ln2): dot(F,F) = sim*2/ln2 -> exp2 direct.
// Single bf16 product (validated r8-r12: absmax 0.0 vs reference).
#define SQS 1.6986436f

// Tiled F layout: for each 32-row group G (400 groups), each kc (16-K chunk,
// 8 chunks), 64 granules of 16B lane-ordered for mfma_32x32x16_bf16 operands.
// One fragment load = contiguous 1KB wave load at G*8192 + kc*1024 + lane*16.

typedef __bf16 bf16x8 __attribute__((ext_vector_type(8)));
typedef float f32x16 __attribute__((ext_vector_type(16)));

#define MFMA32(a, b, c) __builtin_amdgcn_mfma_f32_32x32x16_bf16(a, b, c, 0, 0, 0)

__device__ inline unsigned short f2bf(float x) {
  unsigned u = __float_as_uint(x);
  unsigned r = (u + 0x7fffu + ((u >> 16) & 1u)) >> 16;
  return (unsigned short)r;
}

// ---------------------------------------------------------------------------
// Kernel 1: candidate collection (r9, validated). Zeroes node-C tickets.
// ---------------------------------------------------------------------------
__global__ void cand_kernel(const float* __restrict__ prob, int* __restrict__ candCnt,
                            int* __restrict__ candIdx, float* __restrict__ candVal,
                            int* __restrict__ tickets) {
  __shared__ int lcnt[CC];
  const int b = blockIdx.x, t = threadIdx.x;
  if (b == 0 && t == 0) { tickets[0] = 0; tickets[1] = 0; }
  if (t < CC) lcnt[t] = 0;
  __syncthreads();
  const int base = b * RPP * CC;
  for (int i = t; i < RPP * CC; i += 256) {
    const float v = prob[base + i];
    if (v >= TCAND) {
      const int r = i / CC, c = i - r * CC;
      const int slot = atomicAdd(&lcnt[c], 1);
      if (slot < PCAP) {
        candIdx[(b * CC + c) * PCAP + slot] = b * RPP + r;
        candVal[(b * CC + c) * PCAP + slot] = v;
      }
    }
  }
  __syncthreads();
  if (t < CC) candCnt[b * CC + t] = lcnt[t];
}

// ---------------------------------------------------------------------------
// PARALLEL bin selection (r12, validated): suffix-sum ladder + crossing pick.
// ---------------------------------------------------------------------------
#define PICK_BIN()                                                             \
  {                                                                            \
    _Pragma("unroll")                                                          \
    for (int d = 1; d < 256; d <<= 1) {                                        \
      int v = (t + d < 256) ? hist[t + d] : 0;                                 \
      __syncthreads();                                                         \
      hist[t] += v;                                                            \
      __syncthreads();                                                         \
    }                                                                          \
    const int Sb = hist[t];                                                    \
    const int Sb1 = (t == 255) ? 0 : hist[t + 1];                              \
    if (Sb >= krem && Sb1 < krem) { sChosen = t; sKrem = krem - Sb1; }         \
    __syncthreads();                                                           \
  }

// ---------------------------------------------------------------------------
// Kernel 2: FUSED top-K select (topkL in LDS) + wave-per-row gather/norm.
// Phase 2 math identical to r12's gather_norm (bitwise-same F output).
// ---------------------------------------------------------------------------
__global__ void selgather_kernel(const float* __restrict__ prob,
                                 const int* __restrict__ candCnt,
                                 const int* __restrict__ candIdx,
                                 const float* __restrict__ candVal,
                                 const float* __restrict__ zi,
                                 const float* __restrict__ zj,
                                 char* __restrict__ FT) {
  __shared__ float vals[MAXCAND];
  __shared__ int   idxs[MAXCAND];
  __shared__ int hist[256];
  __shared__ int pref[NPART + 1];
  __shared__ int cntL[NPART];
  __shared__ int topkL[KK];
  __shared__ int eqIdx[256];
  __shared__ int sChosen, sKrem, gtc, eqc, bad;
  const int c = blockIdx.x, t = threadIdx.x;

  if (t == 0) bad = 0;
  __syncthreads();
  if (t < NPART) {
    int cnt_p = candCnt[t * CC + c];
    cntL[t] = cnt_p;
    if (cnt_p > PCAP) bad = 1;
    int x = cnt_p;
#pragma unroll
    for (int d = 1; d < 64; d <<= 1) {
      int y = __shfl_up(x, d, 64);
      if (t >= d) x += y;
    }
    pref[t + 1] = x;
    if (t == 0) pref[0] = 0;
  }
  __syncthreads();
  const int total = pref[NPART];

  if (!bad && total >= KK && total <= MAXCAND) {
    // ---- coalesced candidate gather into LDS ----
    for (int idx = t; idx < NPART * PCAP; idx += 256) {
      const int pt = idx >> 5, sl = idx & 31;
      if (sl < cntL[pt]) {
        const int o = pref[pt] + sl;
        vals[o] = candVal[(pt * CC + c) * PCAP + sl];
        idxs[o] = candIdx[(pt * CC + c) * PCAP + sl];
      }
    }
    __syncthreads();
    unsigned prefix = 0;
    int krem = KK;
    for (int pass = 0; pass < 4; ++pass) {
      const int shift = 24 - pass * 8;
      hist[t] = 0;
      __syncthreads();
      for (int j = t; j < total; j += 256) {
        unsigned u = __float_as_uint(vals[j]);
        bool match = (pass == 0) || ((u >> (shift + 8)) == (prefix >> (shift + 8)));
        if (match) atomicAdd(&hist[(u >> shift) & 255], 1);
      }
      __syncthreads();
      PICK_BIN()
      prefix |= ((unsigned)sChosen) << shift;
      krem = sKrem;
      __syncthreads();
    }
    const unsigned T = prefix;
    if (t == 0) { gtc = 0; eqc = 0; }
    __syncthreads();
    for (int j = t; j < total; j += 256) {
      unsigned u = __float_as_uint(vals[j]);
      if (u > T) {
        int pos = atomicAdd(&gtc, 1);
        topkL[pos] = idxs[j];
      } else if (u == T) {
        int e = atomicAdd(&eqc, 1);
        if (e < 256) eqIdx[e] = idxs[j];
      }
    }
    __syncthreads();
    if (t == 0) {
      int base = gtc;
      int ec = eqc < 256 ? eqc : 256;
      for (int j2 = 0; j2 < krem; ++j2) {
        int bi = -1, bv = 0x7fffffff;
        for (int q = 0; q < ec; ++q) {
          int v = eqIdx[q];
          if (v >= 0 && v < bv) { bv = v; bi = q; }
        }
        topkL[base + j2] = bv;
        eqIdx[bi] = -1;
      }
    }
  } else {
    // ---- exact fallback: full strided column radix select ----
    unsigned prefix = 0;
    int krem = KK;
    for (int pass = 0; pass < 4; ++pass) {
      const int shift = 24 - pass * 8;
      hist[t] = 0;
      __syncthreads();
      for (int i = t; i < BB; i += 256) {
        unsigned u = __float_as_uint(prob[i * CC + c]);
        bool match = (pass == 0) || ((u >> (shift + 8)) == (prefix >> (shift + 8)));
        if (match) atomicAdd(&hist[(u >> shift) & 255], 1);
      }
      __syncthreads();
      PICK_BIN()
      prefix |= ((unsigned)sChosen) << shift;
      krem = sKrem;
      __syncthreads();
    }
    const unsigned T = prefix;
    if (t == 0) { gtc = 0; eqc = 0; }
    __syncthreads();
    for (int i = t; i < BB; i += 256) {
      unsigned u = __float_as_uint(prob[i * CC + c]);
      if (u > T) {
        int pos = atomicAdd(&gtc, 1);
        topkL[pos] = i;
      } else if (u == T) {
        int e = atomicAdd(&eqc, 1);
        if (e < 256) eqIdx[e] = i;
      }
    }
    __syncthreads();
    if (t == 0) {
      int base = gtc;
      int ec = eqc < 256 ? eqc : 256;
      for (int j = 0; j < krem; ++j) {
        int bi = -1, bv = 0x7fffffff;
        for (int q = 0; q < ec; ++q) {
          int v = eqIdx[q];
          if (v >= 0 && v < bv) { bv = v; bi = q; }
        }
        topkL[base + j] = bv;
        eqIdx[bi] = -1;
      }
    }
  }

  // ---- Phase 2: wave-per-row gather + normalize + tiled bf16 write ----
  __syncthreads();
  const int lane = t & 63, wv = t >> 6;
  for (int it = 0; it < 64; ++it) {
    const int p = wv * 64 + it;
    const int idx = topkL[p & (KK - 1)];
    const float* src = (p < KK ? zi : zj) + (size_t)idx * DD;
    float2 v = ((const float2*)src)[lane];
    float ss = fmaf(v.x, v.x, v.y * v.y);
#pragma unroll
    for (int m = 1; m < 64; m <<= 1) ss += __shfl_xor(ss, m, 64);
    const float scale = SQS / fmaxf(sqrtf(ss), 1e-8f);
    unsigned short ah = f2bf(v.x * scale), bh = f2bf(v.y * scale);
    unsigned hp = ((unsigned)bh << 16) | ah;
    const int gw = c * 256 + p;
    const int k2 = 2 * lane;
    const int kc = k2 >> 4;
    const int kk = k2 & 15;
    const size_t off = (size_t)(gw >> 5) * 8192 + (size_t)kc * 1024 +
                       (size_t)(((kk >> 3) * 32 + (gw & 31)) * 16 + (kk & 7) * 2);
    *(unsigned*)(FT + off) = hp;
  }
}

// ---------------------------------------------------------------------------
// Kernel 3: PANELIZED symmetric sim + FUSED finalize via device-scope ticket.
// Every block: sim work (or none for empty chunks) -> threadfence ->
// atomicAdd(done). Blocks 0..49 then spin until done==SIMGRID (deadlock-free:
// spinners occupy <=50 CUs; the other blocks never depend on them), re-fence,
// and run the r12 finalize body; second ticket -> last block writes mean.
// ---------------------------------------------------------------------------
__global__ __launch_bounds__(128, 2) void simfin_kernel(
    const char* __restrict__ F, float* __restrict__ part,
    float* __restrict__ ownArr, float* __restrict__ posArr,
    int* __restrict__ tickets, float* __restrict__ partial,
    float* __restrict__ out) {
  __shared__ float colLds[2][1024];
  const int tid = threadIdx.x;
  const int lane = tid & 63, wave = tid >> 6;
  const int lh2 = lane >> 5;
  const size_t lo16 = (size_t)lane * 16;

  f32x16 Z = {};

#define LOADB(BUF, GIDX) {                                                     \
    _Pragma("unroll")                                                          \
    for (int kc = 0; kc < 8; ++kc)                                             \
      BUF[kc] = *(const bf16x8*)(F + (size_t)(GIDX) * 8192 + kc * 1024 + lo16);\
  }

  if (blockIdx.x < NBLK * NCHUNK) {
    const int I = blockIdx.x / NCHUNK, q = blockIdx.x - I * NCHUNK;
    const int J0 = I + q * CHT;
    if (J0 < NBLK) {                               // non-empty chunk
      const int nt = min(CHT, NBLK - J0);
      const int S = nt * 4;
      const int G0 = J0 * 4;
      const int Ga = I * 4 + wave * 2;

      bf16x8 A0[8], A1[8];
#pragma unroll
      for (int kc = 0; kc < 8; ++kc) {
        A0[kc] = *(const bf16x8*)(F + (size_t)Ga * 8192 + kc * 1024 + lo16);
        A1[kc] = *(const bf16x8*)(F + (size_t)(Ga + 1) * 8192 + kc * 1024 + lo16);
      }
      bf16x8 b0[8], b1[8];
      f32x16 aA0, aA1, aB0, aB1;
      float rAcc0[16], rAcc1[16];
#pragma unroll
      for (int r = 0; r < 16; ++r) { rAcc0[r] = 0.f; rAcc1[r] = 0.f; }
      float colv = 0.f;

#define PROC(AC0, AC1, BB_, AP0, AP1)                                          \
      AC0 = MFMA32(A0[0], BB_[0], Z); AC1 = MFMA32(A1[0], BB_[0], Z);          \
      _Pragma("unroll")                                                        \
      for (int kc = 1; kc < 8; ++kc) {                                         \
        AC0 = MFMA32(A0[kc], BB_[kc], AC0);                                    \
        AC1 = MFMA32(A1[kc], BB_[kc], AC1);                                    \
        const int r0 = 2 * (kc - 1), r1 = r0 + 1;                              \
        float e0 = __builtin_amdgcn_exp2f(AP0[r0]);                            \
        float e1 = __builtin_amdgcn_exp2f(AP0[r1]);                            \
        float e2 = __builtin_amdgcn_exp2f(AP1[r0]);                            \
        float e3 = __builtin_amdgcn_exp2f(AP1[r1]);                            \
        rAcc0[r0] += e0; rAcc0[r1] += e1; rAcc1[r0] += e2; rAcc1[r1] += e3;    \
        colv += (e0 + e1) + (e2 + e3);                                         \
      }                                                                        \
      { float e0 = __builtin_amdgcn_exp2f(AP0[14]);                            \
        float e1 = __builtin_amdgcn_exp2f(AP0[15]);                            \
        float e2 = __builtin_amdgcn_exp2f(AP1[14]);                            \
        float e3 = __builtin_amdgcn_exp2f(AP1[15]);                            \
        rAcc0[14] += e0; rAcc0[15] += e1; rAcc1[14] += e2; rAcc1[15] += e3;    \
        colv += (e0 + e1) + (e2 + e3); }

#define FINCOL(S_) {                                                           \
      float cv = colv + __shfl_xor(colv, 32, 64);                              \
      if (lane < 32) colLds[wave][(S_) * 32 + lane] = cv;                      \
      colv = 0.f; }

      LOADB(b0, G0)
      aA0 = MFMA32(A0[0], b0[0], Z); aA1 = MFMA32(A1[0], b0[0], Z);
#pragma unroll
      for (int kc = 1; kc < 8; ++kc) {
        aA0 = MFMA32(A0[kc], b0[kc], aA0);
        aA1 = MFMA32(A1[kc], b0[kc], aA1);
      }
      LOADB(b1, G0 + 1)

      int s = 1;
      for (; s + 1 < S; s += 2) {
        PROC(aB0, aB1, b1, aA0, aA1)
        FINCOL(s - 1)
        LOADB(b0, G0 + s + 1)
        PROC(aA0, aA1, b0, aB0, aB1)
        FINCOL(s)
        LOADB(b1, G0 + s + 2)
      }
      PROC(aB0, aB1, b1, aA0, aA1)
      FINCOL(S - 2)
#pragma unroll
      for (int r = 0; r < 16; ++r) {
        float e0 = __builtin_amdgcn_exp2f(aB0[r]);
        float e1 = __builtin_amdgcn_exp2f(aB1[r]);
        rAcc0[r] += e0; rAcc1[r] += e1;
        colv += e0 + e1;
      }
      FINCOL(S - 1)
#undef PROC
#undef FINCOL

      __syncthreads();
      for (int idx = tid; idx < S * 32; idx += 128) {
        const int J = J0 + (idx >> 7);
        if (J != I)
          part[(size_t)I * MM + J * 128 + (idx & 127)] = colLds[0][idx] + colLds[1][idx];
      }

#pragma unroll
      for (int m = 1; m < 32; m <<= 1)
#pragma unroll
        for (int r = 0; r < 16; ++r) {
          rAcc0[r] += __shfl_xor(rAcc0[r], m, 32);
          rAcc1[r] += __shfl_xor(rAcc1[r], m, 32);
        }
      if ((lane & 31) == 0) {
        const int rbase = I * 128 + wave * 64;
#pragma unroll
        for (int r = 0; r < 16; ++r) {
          const int rl = (r & 3) + 8 * (r >> 2) + 4 * lh2;
          part[(size_t)(NBLK + q) * MM + rbase + rl] = rAcc0[r];
          part[(size_t)(NBLK + q) * MM + rbase + 32 + rl] = rAcc1[r];
        }
      }
    }
  } else {
    // ================= own/pos path (r9, validated) =================
    const int bid2 = blockIdx.x - NBLK * NCHUNK;
    const int c = bid2 >> 1, q2 = bid2 & 1;
    const int Ga = c * 8 + q2 * 4 + wave * 2;
    const int c8 = c * 8;

    bf16x8 A0[8], A1[8];
#pragma unroll
    for (int kc = 0; kc < 8; ++kc) {
      A0[kc] = *(const bf16x8*)(F + (size_t)Ga * 8192 + kc * 1024 + lo16);
      A1[kc] = *(const bf16x8*)(F + (size_t)(Ga + 1) * 8192 + kc * 1024 + lo16);
    }
    bf16x8 b0[8], b1[8];
    float rAcc0[16], rAcc1[16];
#pragma unroll
    for (int r = 0; r < 16; ++r) { rAcc0[r] = 0.f; rAcc1[r] = 0.f; }

#define OWNTILE(BB_) {                                                         \
    f32x16 a0 = MFMA32(A0[0], BB_[0], Z), a1 = MFMA32(A1[0], BB_[0], Z);       \
    _Pragma("unroll")                                                          \
    for (int kc = 1; kc < 8; ++kc) {                                           \
      a0 = MFMA32(A0[kc], BB_[kc], a0); a1 = MFMA32(A1[kc], BB_[kc], a1); }    \
    _Pragma("unroll")                                                          \
    for (int r = 0; r < 16; ++r) {                                             \
      rAcc0[r] += __builtin_amdgcn_exp2f(a0[r]);                               \
      rAcc1[r] += __builtin_amdgcn_exp2f(a1[r]); } }

#define REDUCEW(DST) {                                                         \
    float t0[16], t1[16];                                                      \
    _Pragma("unroll")                                                          \
    for (int r = 0; r < 16; ++r) { t0[r] = rAcc0[r]; t1[r] = rAcc1[r]; }       \
    _Pragma("unroll")                                                          \
    for (int m = 1; m < 32; m <<= 1)                                           \
      _Pragma("unroll")                                                        \
      for (int r = 0; r < 16; ++r) {                                           \
        t0[r] += __shfl_xor(t0[r], m, 32);                                     \
        t1[r] += __shfl_xor(t1[r], m, 32); }                                   \
    if ((lane & 31) == 0) {                                                    \
      const int rbase = c * 256 + q2 * 128 + wave * 64;                        \
      _Pragma("unroll")                                                        \
      for (int r = 0; r < 16; ++r) {                                           \
        const int rl = (r & 3) + 8 * (r >> 2) + 4 * lh2;                       \
        DST[rbase + rl] = t0[r];                                               \
        DST[rbase + 32 + rl] = t1[r]; } } }

    LOADB(b0, c8 + 0)
    LOADB(b1, c8 + 1)  OWNTILE(b0)
    LOADB(b0, c8 + 2)  OWNTILE(b1)
    LOADB(b1, c8 + 3)  OWNTILE(b0)
    LOADB(b0, c8 + 4)  OWNTILE(b1)
    REDUCEW(posArr)
    LOADB(b1, c8 + 5)  OWNTILE(b0)
    LOADB(b0, c8 + 6)  OWNTILE(b1)
    LOADB(b1, c8 + 7)  OWNTILE(b0)
    OWNTILE(b1)
    REDUCEW(ownArr)
#undef OWNTILE
#undef REDUCEW
  }
#undef LOADB

  // ---- completion ticket (every block, including empty chunks) ----
  __syncthreads();
  if (tid == 0) {
    __threadfence();   // make this block's part/own/pos writes device-visible
    __hip_atomic_fetch_add(&tickets[0], 1, __ATOMIC_ACQ_REL,
                           __HIP_MEMORY_SCOPE_AGENT);
  }

  // ---- fused finalize: blocks 0..49 ----
  if (blockIdx.x < MM / 256) {
    if (tid == 0) {
      while (__hip_atomic_load(&tickets[0], __ATOMIC_ACQUIRE,
                               __HIP_MEMORY_SCOPE_AGENT) < SIMGRID)
        __builtin_amdgcn_s_sleep(2);
    }
    __syncthreads();
    __threadfence();

    __shared__ float red[2];
    // 128 threads -> each handles 2 rows of this 256-row chunk
    float rlsum = 0.f;
#pragma unroll
    for (int h = 0; h < 2; ++h) {
      const int p = blockIdx.x * 256 + h * 128 + tid;
      const int pb = p >> 7;
      float a = 0.f;
      for (int b = 0; b < pb; ++b) a += part[(size_t)b * MM + p];
      const int qmax = (NBLK - 1 - pb) >> 3;
      for (int q = 0; q <= qmax; ++q) a += part[(size_t)(NBLK + q) * MM + p];
      rlsum += logf(a - ownArr[p]) - logf(posArr[p]);
    }
#pragma unroll
    for (int m = 1; m < 64; m <<= 1) rlsum += __shfl_xor(rlsum, m, 64);
    if ((tid & 63) == 0) red[tid >> 6] = rlsum;
    __syncthreads();
    if (tid == 0) {
      const float bsum = red[0] + red[1];
      __hip_atomic_store(&partial[blockIdx.x], bsum, __ATOMIC_RELEASE,
                         __HIP_MEMORY_SCOPE_AGENT);
      const int old = __hip_atomic_fetch_add(&tickets[1], 1, __ATOMIC_ACQ_REL,
                                             __HIP_MEMORY_SCOPE_AGENT);
      if (old == (MM / 256) - 1) {        // last block: deterministic sum
        float s = 0.f;
        for (int i = 0; i < MM / 256; ++i)
          s += __hip_atomic_load(&partial[i], __ATOMIC_ACQUIRE,
                                 __HIP_MEMORY_SCOPE_AGENT);
        out[0] = s * (1.0f / MM);
      }
    }
  }
}

extern "C" void kernel_launch(void* const* d_in, const int* in_sizes, int n_in,
                              void* d_out, int out_size, void* d_ws, size_t ws_size,
                              hipStream_t stream) {
  const float* prob = (const float*)d_in[0];
  const float* zi   = (const float*)d_in[1];
  const float* zj   = (const float*)d_in[2];
  float* out = (float*)d_out;

  char* ws = (char*)d_ws;
  char*  FT       = ws;                                  // 3,276,800 B
  float* part     = (float*)(ws + 3276800);              // 113*12800*4 = 5,785,600 B
  // cand buffers alias the (not-yet-live) part region: dead before sim writes.
  int*   candCnt  = (int*)  (ws + 3276800);              //    12,800 B
  int*   candIdx  = (int*)  (ws + 3276800 + 16384);      //   409,600 B
  float* candVal  = (float*)(ws + 3276800 + 430080);     //   409,600 B
  float* ownArr   = (float*)(ws + 9062400);              //    51,200 B
  float* posArr   = (float*)(ws + 9113600);              //    51,200 B
  float* partial  = (float*)(ws + 9164800);              //       256 B
  int*   tickets  = (int*)  (ws + 9165056);              //         8 B

  cand_kernel     <<<NPART, 256, 0, stream>>>(prob, candCnt, candIdx, candVal, tickets);
  selgather_kernel<<<CC, 256, 0, stream>>>(prob, candCnt, candIdx, candVal, zi, zj, FT);
  simfin_kernel   <<<SIMGRID, 128, 0, stream>>>(FT, part, ownArr, posArr, tickets, partial, out);
}

// Round 14
// 244.521 us; speedup vs baseline: 1.0401x; 1.0401x over previous
//
#include <hip/hip_runtime.h>
#include <math.h>

#define BB 16384      // B
#define CC 50         // clusters
#define KK 128        // top-K
#define DD 128        // feature dim
#define MM 12800      // CC*2*KK rows of F
#define NBLK 100      // 128-row blocks of F
#define NCHUNK 13     // J-chunks per row (chunk = 8 tiles)
#define CHT 8         // tiles per chunk
#define MAXCAND 2048
#define TCAND 0.97f
#define NPART 64      // candidate partitions (256 rows each)
#define RPP 256       // rows per partition
#define PCAP 32       // per (partition,cluster) capacity; expected ~7.7
#define SIMGRID (NBLK * NCHUNK + 2 * CC)   // 1400
#define NFIN (MM / 256)                    // 50 finalize blocks (the LAST 50)
// F rows pre-scaled by SQS = sqrt(2/ln2): dot(F,F) = sim*2/ln2 -> exp2 direct.
// Single bf16 product (validated r8-r13: absmax 0.0 vs reference).
#define SQS 1.6986436f

// Tiled F layout: for each 32-row group G (400 groups), each kc (16-K chunk,
// 8 chunks), 64 granules of 16B lane-ordered for mfma_32x32x16_bf16 operands.
// One fragment load = contiguous 1KB wave load at G*8192 + kc*1024 + lane*16.

typedef __bf16 bf16x8 __attribute__((ext_vector_type(8)));
typedef float f32x16 __attribute__((ext_vector_type(16)));

#define MFMA32(a, b, c) __builtin_amdgcn_mfma_f32_32x32x16_bf16(a, b, c, 0, 0, 0)

__device__ inline unsigned short f2bf(float x) {
  unsigned u = __float_as_uint(x);
  unsigned r = (u + 0x7fffu + ((u >> 16) & 1u)) >> 16;
  return (unsigned short)r;
}

// ---------------------------------------------------------------------------
// Kernel 1: candidate collection (r9, validated). Block 0 zeroes the
// completion-flag arrays (flags[SIMGRID] + flag2[NFIN]) for this launch.
// ---------------------------------------------------------------------------
__global__ void cand_kernel(const float* __restrict__ prob, int* __restrict__ candCnt,
                            int* __restrict__ candIdx, float* __restrict__ candVal,
                            int* __restrict__ flags) {
  __shared__ int lcnt[CC];
  const int b = blockIdx.x, t = threadIdx.x;
  if (b == 0) {
    for (int i = t; i < SIMGRID + NFIN; i += 256) flags[i] = 0;
  }
  if (t < CC) lcnt[t] = 0;
  __syncthreads();
  const int base = b * RPP * CC;
  for (int i = t; i < RPP * CC; i += 256) {
    const float v = prob[base + i];
    if (v >= TCAND) {
      const int r = i / CC, c = i - r * CC;
      const int slot = atomicAdd(&lcnt[c], 1);
      if (slot < PCAP) {
        candIdx[(b * CC + c) * PCAP + slot] = b * RPP + r;
        candVal[(b * CC + c) * PCAP + slot] = v;
      }
    }
  }
  __syncthreads();
  if (t < CC) candCnt[b * CC + t] = lcnt[t];
}

// ---------------------------------------------------------------------------
// PARALLEL bin selection (r12, validated): suffix-sum ladder + crossing pick.
// ---------------------------------------------------------------------------
#define PICK_BIN()                                                             \
  {                                                                            \
    _Pragma("unroll")                                                          \
    for (int d = 1; d < 256; d <<= 1) {                                        \
      int v = (t + d < 256) ? hist[t + d] : 0;                                 \
      __syncthreads();                                                         \
      hist[t] += v;                                                            \
      __syncthreads();                                                         \
    }                                                                          \
    const int Sb = hist[t];                                                    \
    const int Sb1 = (t == 255) ? 0 : hist[t + 1];                              \
    if (Sb >= krem && Sb1 < krem) { sChosen = t; sKrem = krem - Sb1; }         \
    __syncthreads();                                                           \
  }

// ---------------------------------------------------------------------------
// Kernel 2: FUSED top-K select (topkL in LDS) + wave-per-row gather/norm
// (r13, validated: passed with absmax 0.0).
// ---------------------------------------------------------------------------
__global__ void selgather_kernel(const float* __restrict__ prob,
                                 const int* __restrict__ candCnt,
                                 const int* __restrict__ candIdx,
                                 const float* __restrict__ candVal,
                                 const float* __restrict__ zi,
                                 const float* __restrict__ zj,
                                 char* __restrict__ FT) {
  __shared__ float vals[MAXCAND];
  __shared__ int   idxs[MAXCAND];
  __shared__ int hist[256];
  __shared__ int pref[NPART + 1];
  __shared__ int cntL[NPART];
  __shared__ int topkL[KK];
  __shared__ int eqIdx[256];
  __shared__ int sChosen, sKrem, gtc, eqc, bad;
  const int c = blockIdx.x, t = threadIdx.x;

  if (t == 0) bad = 0;
  __syncthreads();
  if (t < NPART) {
    int cnt_p = candCnt[t * CC + c];
    cntL[t] = cnt_p;
    if (cnt_p > PCAP) bad = 1;
    int x = cnt_p;
#pragma unroll
    for (int d = 1; d < 64; d <<= 1) {
      int y = __shfl_up(x, d, 64);
      if (t >= d) x += y;
    }
    pref[t + 1] = x;
    if (t == 0) pref[0] = 0;
  }
  __syncthreads();
  const int total = pref[NPART];

  if (!bad && total >= KK && total <= MAXCAND) {
    for (int idx = t; idx < NPART * PCAP; idx += 256) {
      const int pt = idx >> 5, sl = idx & 31;
      if (sl < cntL[pt]) {
        const int o = pref[pt] + sl;
        vals[o] = candVal[(pt * CC + c) * PCAP + sl];
        idxs[o] = candIdx[(pt * CC + c) * PCAP + sl];
      }
    }
    __syncthreads();
    unsigned prefix = 0;
    int krem = KK;
    for (int pass = 0; pass < 4; ++pass) {
      const int shift = 24 - pass * 8;
      hist[t] = 0;
      __syncthreads();
      for (int j = t; j < total; j += 256) {
        unsigned u = __float_as_uint(vals[j]);
        bool match = (pass == 0) || ((u >> (shift + 8)) == (prefix >> (shift + 8)));
        if (match) atomicAdd(&hist[(u >> shift) & 255], 1);
      }
      __syncthreads();
      PICK_BIN()
      prefix |= ((unsigned)sChosen) << shift;
      krem = sKrem;
      __syncthreads();
    }
    const unsigned T = prefix;
    if (t == 0) { gtc = 0; eqc = 0; }
    __syncthreads();
    for (int j = t; j < total; j += 256) {
      unsigned u = __float_as_uint(vals[j]);
      if (u > T) {
        int pos = atomicAdd(&gtc, 1);
        topkL[pos] = idxs[j];
      } else if (u == T) {
        int e = atomicAdd(&eqc, 1);
        if (e < 256) eqIdx[e] = idxs[j];
      }
    }
    __syncthreads();
    if (t == 0) {
      int base = gtc;
      int ec = eqc < 256 ? eqc : 256;
      for (int j2 = 0; j2 < krem; ++j2) {
        int bi = -1, bv = 0x7fffffff;
        for (int q = 0; q < ec; ++q) {
          int v = eqIdx[q];
          if (v >= 0 && v < bv) { bv = v; bi = q; }
        }
        topkL[base + j2] = bv;
        eqIdx[bi] = -1;
      }
    }
  } else {
    unsigned prefix = 0;
    int krem = KK;
    for (int pass = 0; pass < 4; ++pass) {
      const int shift = 24 - pass * 8;
      hist[t] = 0;
      __syncthreads();
      for (int i = t; i < BB; i += 256) {
        unsigned u = __float_as_uint(prob[i * CC + c]);
        bool match = (pass == 0) || ((u >> (shift + 8)) == (prefix >> (shift + 8)));
        if (match) atomicAdd(&hist[(u >> shift) & 255], 1);
      }
      __syncthreads();
      PICK_BIN()
      prefix |= ((unsigned)sChosen) << shift;
      krem = sKrem;
      __syncthreads();
    }
    const unsigned T = prefix;
    if (t == 0) { gtc = 0; eqc = 0; }
    __syncthreads();
    for (int i = t; i < BB; i += 256) {
      unsigned u = __float_as_uint(prob[i * CC + c]);
      if (u > T) {
        int pos = atomicAdd(&gtc, 1);
        topkL[pos] = i;
      } else if (u == T) {
        int e = atomicAdd(&eqc, 1);
        if (e < 256) eqIdx[e] = i;
      }
    }
    __syncthreads();
    if (t == 0) {
      int base = gtc;
      int ec = eqc < 256 ? eqc : 256;
      for (int j = 0; j < krem; ++j) {
        int bi = -1, bv = 0x7fffffff;
        for (int q = 0; q < ec; ++q) {
          int v = eqIdx[q];
          if (v >= 0 && v < bv) { bv = v; bi = q; }
        }
        topkL[base + j] = bv;
        eqIdx[bi] = -1;
      }
    }
  }

  // ---- Phase 2: wave-per-row gather + normalize + tiled bf16 write ----
  __syncthreads();
  const int lane = t & 63, wv = t >> 6;
  for (int it = 0; it < 64; ++it) {
    const int p = wv * 64 + it;
    const int idx = topkL[p & (KK - 1)];
    const float* src = (p < KK ? zi : zj) + (size_t)idx * DD;
    float2 v = ((const float2*)src)[lane];
    float ss = fmaf(v.x, v.x, v.y * v.y);
#pragma unroll
    for (int m = 1; m < 64; m <<= 1) ss += __shfl_xor(ss, m, 64);
    const float scale = SQS / fmaxf(sqrtf(ss), 1e-8f);
    unsigned short ah = f2bf(v.x * scale), bh = f2bf(v.y * scale);
    unsigned hp = ((unsigned)bh << 16) | ah;
    const int gw = c * 256 + p;
    const int k2 = 2 * lane;
    const int kc = k2 >> 4;
    const int kk = k2 & 15;
    const size_t off = (size_t)(gw >> 5) * 8192 + (size_t)kc * 1024 +
                       (size_t)(((kk >> 3) * 32 + (gw & 31)) * 16 + (kk & 7) * 2);
    *(unsigned*)(FT + off) = hp;
  }
}

// ---------------------------------------------------------------------------
// Kernel 3: PANELIZED symmetric sim + fused finalize, CONTENTION-FREE sync.
// Every block: sim work -> threadfence -> release-store its OWN flag (1400
// distinct lines; zero same-address RMW — r13's 1400 contended atomicAdds to
// one line cost ~168us). The LAST NFIN blocks then poll all flags in
// parallel (11 loads/thread/sweep + __syncthreads_and), re-fence, and run
// the finalize body; partials publish via release-store + flag2; block
// SIMGRID-NFIN polls flag2 lane-parallel and wave-reduces (deterministic).
// Deadlock-free: spinners (50 blocks) << capacity; no other block waits.
// ---------------------------------------------------------------------------
__global__ __launch_bounds__(128, 2) void simfin_kernel(
    const char* __restrict__ F, float* __restrict__ part,
    float* __restrict__ ownArr, float* __restrict__ posArr,
    int* __restrict__ flags, float* __restrict__ partial,
    float* __restrict__ out) {
  __shared__ float colLds[2][1024];
  __shared__ float red[2];
  const int tid = threadIdx.x;
  const int lane = tid & 63, wave = tid >> 6;
  const int lh2 = lane >> 5;
  const size_t lo16 = (size_t)lane * 16;

  f32x16 Z = {};

#define LOADB(BUF, GIDX) {                                                     \
    _Pragma("unroll")                                                          \
    for (int kc = 0; kc < 8; ++kc)                                             \
      BUF[kc] = *(const bf16x8*)(F + (size_t)(GIDX) * 8192 + kc * 1024 + lo16);\
  }

  if (blockIdx.x < NBLK * NCHUNK) {
    const int I = blockIdx.x / NCHUNK, q = blockIdx.x - I * NCHUNK;
    const int J0 = I + q * CHT;
    if (J0 < NBLK) {                               // non-empty chunk
      const int nt = min(CHT, NBLK - J0);
      const int S = nt * 4;
      const int G0 = J0 * 4;
      const int Ga = I * 4 + wave * 2;

      bf16x8 A0[8], A1[8];
#pragma unroll
      for (int kc = 0; kc < 8; ++kc) {
        A0[kc] = *(const bf16x8*)(F + (size_t)Ga * 8192 + kc * 1024 + lo16);
        A1[kc] = *(const bf16x8*)(F + (size_t)(Ga + 1) * 8192 + kc * 1024 + lo16);
      }
      bf16x8 b0[8], b1[8];
      f32x16 aA0, aA1, aB0, aB1;
      float rAcc0[16], rAcc1[16];
#pragma unroll
      for (int r = 0; r < 16; ++r) { rAcc0[r] = 0.f; rAcc1[r] = 0.f; }
      float colv = 0.f;

#define PROC(AC0, AC1, BB_, AP0, AP1)                                          \
      AC0 = MFMA32(A0[0], BB_[0], Z); AC1 = MFMA32(A1[0], BB_[0], Z);          \
      _Pragma("unroll")                                                        \
      for (int kc = 1; kc < 8; ++kc) {                                         \
        AC0 = MFMA32(A0[kc], BB_[kc], AC0);                                    \
        AC1 = MFMA32(A1[kc], BB_[kc], AC1);                                    \
        const int r0 = 2 * (kc - 1), r1 = r0 + 1;                              \
        float e0 = __builtin_amdgcn_exp2f(AP0[r0]);                            \
        float e1 = __builtin_amdgcn_exp2f(AP0[r1]);                            \
        float e2 = __builtin_amdgcn_exp2f(AP1[r0]);                            \
        float e3 = __builtin_amdgcn_exp2f(AP1[r1]);                            \
        rAcc0[r0] += e0; rAcc0[r1] += e1; rAcc1[r0] += e2; rAcc1[r1] += e3;    \
        colv += (e0 + e1) + (e2 + e3);                                         \
      }                                                                        \
      { float e0 = __builtin_amdgcn_exp2f(AP0[14]);                            \
        float e1 = __builtin_amdgcn_exp2f(AP0[15]);                            \
        float e2 = __builtin_amdgcn_exp2f(AP1[14]);                            \
        float e3 = __builtin_amdgcn_exp2f(AP1[15]);                            \
        rAcc0[14] += e0; rAcc0[15] += e1; rAcc1[14] += e2; rAcc1[15] += e3;    \
        colv += (e0 + e1) + (e2 + e3); }

#define FINCOL(S_) {                                                           \
      float cv = colv + __shfl_xor(colv, 32, 64);                              \
      if (lane < 32) colLds[wave][(S_) * 32 + lane] = cv;                      \
      colv = 0.f; }

      LOADB(b0, G0)
      aA0 = MFMA32(A0[0], b0[0], Z); aA1 = MFMA32(A1[0], b0[0], Z);
#pragma unroll
      for (int kc = 1; kc < 8; ++kc) {
        aA0 = MFMA32(A0[kc], b0[kc], aA0);
        aA1 = MFMA32(A1[kc], b0[kc], aA1);
      }
      LOADB(b1, G0 + 1)

      int s = 1;
      for (; s + 1 < S; s += 2) {
        PROC(aB0, aB1, b1, aA0, aA1)
        FINCOL(s - 1)
        LOADB(b0, G0 + s + 1)
        PROC(aA0, aA1, b0, aB0, aB1)
        FINCOL(s)
        LOADB(b1, G0 + s + 2)
      }
      PROC(aB0, aB1, b1, aA0, aA1)
      FINCOL(S - 2)
#pragma unroll
      for (int r = 0; r < 16; ++r) {
        float e0 = __builtin_amdgcn_exp2f(aB0[r]);
        float e1 = __builtin_amdgcn_exp2f(aB1[r]);
        rAcc0[r] += e0; rAcc1[r] += e1;
        colv += e0 + e1;
      }
      FINCOL(S - 1)
#undef PROC
#undef FINCOL

      __syncthreads();
      for (int idx = tid; idx < S * 32; idx += 128) {
        const int J = J0 + (idx >> 7);
        if (J != I)
          part[(size_t)I * MM + J * 128 + (idx & 127)] = colLds[0][idx] + colLds[1][idx];
      }

#pragma unroll
      for (int m = 1; m < 32; m <<= 1)
#pragma unroll
        for (int r = 0; r < 16; ++r) {
          rAcc0[r] += __shfl_xor(rAcc0[r], m, 32);
          rAcc1[r] += __shfl_xor(rAcc1[r], m, 32);
        }
      if ((lane & 31) == 0) {
        const int rbase = I * 128 + wave * 64;
#pragma unroll
        for (int r = 0; r < 16; ++r) {
          const int rl = (r & 3) + 8 * (r >> 2) + 4 * lh2;
          part[(size_t)(NBLK + q) * MM + rbase + rl] = rAcc0[r];
          part[(size_t)(NBLK + q) * MM + rbase + 32 + rl] = rAcc1[r];
        }
      }
    }
  } else {
    // ================= own/pos path (r9, validated) =================
    const int bid2 = blockIdx.x - NBLK * NCHUNK;
    const int c = bid2 >> 1, q2 = bid2 & 1;
    const int Ga = c * 8 + q2 * 4 + wave * 2;
    const int c8 = c * 8;

    bf16x8 A0[8], A1[8];
#pragma unroll
    for (int kc = 0; kc < 8; ++kc) {
      A0[kc] = *(const bf16x8*)(F + (size_t)Ga * 8192 + kc * 1024 + lo16);
      A1[kc] = *(const bf16x8*)(F + (size_t)(Ga + 1) * 8192 + kc * 1024 + lo16);
    }
    bf16x8 b0[8], b1[8];
    float rAcc0[16], rAcc1[16];
#pragma unroll
    for (int r = 0; r < 16; ++r) { rAcc0[r] = 0.f; rAcc1[r] = 0.f; }

#define OWNTILE(BB_) {                                                         \
    f32x16 a0 = MFMA32(A0[0], BB_[0], Z), a1 = MFMA32(A1[0], BB_[0], Z);       \
    _Pragma("unroll")                                                          \
    for (int kc = 1; kc < 8; ++kc) {                                           \
      a0 = MFMA32(A0[kc], BB_[kc], a0); a1 = MFMA32(A1[kc], BB_[kc], a1); }    \
    _Pragma("unroll")                                                          \
    for (int r = 0; r < 16; ++r) {                                             \
      rAcc0[r] += __builtin_amdgcn_exp2f(a0[r]);                               \
      rAcc1[r] += __builtin_amdgcn_exp2f(a1[r]); } }

#define REDUCEW(DST) {                                                         \
    float t0[16], t1[16];                                                      \
    _Pragma("unroll")                                                          \
    for (int r = 0; r < 16; ++r) { t0[r] = rAcc0[r]; t1[r] = rAcc1[r]; }       \
    _Pragma("unroll")                                                          \
    for (int m = 1; m < 32; m <<= 1)                                           \
      _Pragma("unroll")                                                        \
      for (int r = 0; r < 16; ++r) {                                           \
        t0[r] += __shfl_xor(t0[r], m, 32);                                     \
        t1[r] += __shfl_xor(t1[r], m, 32); }                                   \
    if ((lane & 31) == 0) {                                                    \
      const int rbase = c * 256 + q2 * 128 + wave * 64;                        \
      _Pragma("unroll")                                                        \
      for (int r = 0; r < 16; ++r) {                                           \
        const int rl = (r & 3) + 8 * (r >> 2) + 4 * lh2;                       \
        DST[rbase + rl] = t0[r];                                               \
        DST[rbase + 32 + rl] = t1[r]; } } }

    LOADB(b0, c8 + 0)
    LOADB(b1, c8 + 1)  OWNTILE(b0)
    LOADB(b0, c8 + 2)  OWNTILE(b1)
    LOADB(b1, c8 + 3)  OWNTILE(b0)
    LOADB(b0, c8 + 4)  OWNTILE(b1)
    REDUCEW(posArr)
    LOADB(b1, c8 + 5)  OWNTILE(b0)
    LOADB(b0, c8 + 6)  OWNTILE(b1)
    LOADB(b1, c8 + 7)  OWNTILE(b0)
    OWNTILE(b1)
    REDUCEW(ownArr)
#undef OWNTILE
#undef REDUCEW
  }
#undef LOADB

  // ---- publish completion: per-block flag, NO shared-line RMW ----
  __syncthreads();
  if (tid == 0) {
    __threadfence();   // make this block's part/own/pos writes device-visible
    __hip_atomic_store(&flags[blockIdx.x], 1, __ATOMIC_RELEASE,
                       __HIP_MEMORY_SCOPE_AGENT);
  }

  // ---- fused finalize: LAST NFIN blocks (dispatch last -> minimal spin) ----
  if (blockIdx.x >= SIMGRID - NFIN) {
    const int fb = blockIdx.x - (SIMGRID - NFIN);

    // poll all SIMGRID flags in parallel (11 loads/thread/sweep)
    for (;;) {
      int my = 1;
      for (int i = tid; i < SIMGRID; i += 128)
        my &= __hip_atomic_load(&flags[i], __ATOMIC_ACQUIRE,
                                __HIP_MEMORY_SCOPE_AGENT);
      if (__syncthreads_and(my)) break;
      __builtin_amdgcn_s_sleep(8);
    }
    __threadfence();

    // per-row loss; 128 threads x 2 rows of this 256-row chunk
    float rlsum = 0.f;
#pragma unroll
    for (int h = 0; h < 2; ++h) {
      const int p = fb * 256 + h * 128 + tid;
      const int pb = p >> 7;
      float a = 0.f;
      for (int b = 0; b < pb; ++b) a += part[(size_t)b * MM + p];
      const int qmax = (NBLK - 1 - pb) >> 3;
      for (int q = 0; q <= qmax; ++q) a += part[(size_t)(NBLK + q) * MM + p];
      rlsum += logf(a - ownArr[p]) - logf(posArr[p]);
    }
#pragma unroll
    for (int m = 1; m < 64; m <<= 1) rlsum += __shfl_xor(rlsum, m, 64);
    if ((tid & 63) == 0) red[tid >> 6] = rlsum;
    __syncthreads();
    if (tid == 0) {
      const float bsum = red[0] + red[1];
      __hip_atomic_store(&partial[fb], bsum, __ATOMIC_RELEASE,
                         __HIP_MEMORY_SCOPE_AGENT);
      __hip_atomic_store(&flags[SIMGRID + fb], 1, __ATOMIC_RELEASE,
                         __HIP_MEMORY_SCOPE_AGENT);
    }

    // block fb==0: poll the NFIN partial-flags lane-parallel, sum, write mean
    if (fb == 0) {
      for (;;) {
        int ok = (tid < NFIN)
                     ? __hip_atomic_load(&flags[SIMGRID + tid], __ATOMIC_ACQUIRE,
                                         __HIP_MEMORY_SCOPE_AGENT)
                     : 1;
        if (__syncthreads_and(ok)) break;
        __builtin_amdgcn_s_sleep(2);
      }
      float s = (tid < NFIN) ? partial[tid] : 0.f;   // wave 0 holds all 50
#pragma unroll
      for (int m = 1; m < 64; m <<= 1) s += __shfl_xor(s, m, 64);
      if (tid == 0) out[0] = s * (1.0f / MM);
    }
  }
}

extern "C" void kernel_launch(void* const* d_in, const int* in_sizes, int n_in,
                              void* d_out, int out_size, void* d_ws, size_t ws_size,
                              hipStream_t stream) {
  const float* prob = (const float*)d_in[0];
  const float* zi   = (const float*)d_in[1];
  const float* zj   = (const float*)d_in[2];
  float* out = (float*)d_out;

  char* ws = (char*)d_ws;
  char*  FT       = ws;                                  // 3,276,800 B
  float* part     = (float*)(ws + 3276800);              // 113*12800*4 = 5,785,600 B
  // cand buffers alias the (not-yet-live) part region: dead before sim writes.
  int*   candCnt  = (int*)  (ws + 3276800);              //    12,800 B
  int*   candIdx  = (int*)  (ws + 3276800 + 16384);      //   409,600 B
  float* candVal  = (float*)(ws + 3276800 + 430080);     //   409,600 B
  float* ownArr   = (float*)(ws + 9062400);              //    51,200 B
  float* posArr   = (float*)(ws + 9113600);              //    51,200 B
  float* partial  = (float*)(ws + 9164800);              //       256 B
  int*   flags    = (int*)  (ws + 9165056);              // (1400+50)*4 = 5,800 B

  cand_kernel     <<<NPART, 256, 0, stream>>>(prob, candCnt, candIdx, candVal, flags);
  selgather_kernel<<<CC, 256, 0, stream>>>(prob, candCnt, candIdx, candVal, zi, zj, FT);
  simfin_kernel   <<<SIMGRID, 128, 0, stream>>>(FT, part, ownArr, posArr, flags, partial, out);
}

// Round 15
// 139.410 us; speedup vs baseline: 1.8244x; 1.7540x over previous
//
#include <hip/hip_runtime.h>
#include <math.h>

#define BB 16384      // B
#define CC 50         // clusters
#define KK 128        // top-K
#define DD 128        // feature dim
#define MM 12800      // CC*2*KK rows of F
#define NBLK 100      // 128-row blocks of F
#define NCHUNK 13     // J-chunks per row (chunk = 8 tiles)
#define CHT 8         // tiles per chunk
#define MAXCAND 2048
#define TCAND 0.97f
#define NPART 64      // candidate partitions (256 rows each)
#define RPP 256       // rows per partition
#define PCAP 32       // per (partition,cluster) capacity; expected ~7.7
// F rows pre-scaled by SQS = sqrt(2/ln2): dot(F,F) = sim*2/ln2 -> exp2 direct.
// Single bf16 product (validated r8-r14: absmax 0.0 vs reference).
#define SQS 1.6986436f

// Tiled F layout: for each 32-row group G (400 groups), each kc (16-K chunk,
// 8 chunks), 64 granules of 16B lane-ordered for mfma_32x32x16_bf16 operands.
// One fragment load = contiguous 1KB wave load at G*8192 + kc*1024 + lane*16.
//
// LESSON (r13/r14): intra-kernel producer->consumer sync needs a per-block
// device-scope fence; on 8-XCD gfx950 that L2-writeback tax cost ~150us for
// 1400 blocks. Kernel boundaries batch the same flush once — keep the
// pipeline as separate nodes.

typedef __bf16 bf16x8 __attribute__((ext_vector_type(8)));
typedef float f32x16 __attribute__((ext_vector_type(16)));

#define MFMA32(a, b, c) __builtin_amdgcn_mfma_f32_32x32x16_bf16(a, b, c, 0, 0, 0)

__device__ inline unsigned short f2bf(float x) {
  unsigned u = __float_as_uint(x);
  unsigned r = (u + 0x7fffu + ((u >> 16) & 1u)) >> 16;
  return (unsigned short)r;
}

// ---------------------------------------------------------------------------
// Kernel 1: candidate collection, zero global atomics (r9, validated).
// Zeroes the finalize ticket for this launch.
// ---------------------------------------------------------------------------
__global__ void cand_kernel(const float* __restrict__ prob, int* __restrict__ candCnt,
                            int* __restrict__ candIdx, float* __restrict__ candVal,
                            int* __restrict__ ticket) {
  __shared__ int lcnt[CC];
  const int b = blockIdx.x, t = threadIdx.x;
  if (b == 0 && t == 0) *ticket = 0;
  if (t < CC) lcnt[t] = 0;
  __syncthreads();
  const int base = b * RPP * CC;
  for (int i = t; i < RPP * CC; i += 256) {
    const float v = prob[base + i];
    if (v >= TCAND) {
      const int r = i / CC, c = i - r * CC;
      const int slot = atomicAdd(&lcnt[c], 1);
      if (slot < PCAP) {
        candIdx[(b * CC + c) * PCAP + slot] = b * RPP + r;
        candVal[(b * CC + c) * PCAP + slot] = v;
      }
    }
  }
  __syncthreads();
  if (t < CC) candCnt[b * CC + t] = lcnt[t];
}

// ---------------------------------------------------------------------------
// PARALLEL bin selection (r12, validated): suffix-sum ladder + crossing pick.
// ---------------------------------------------------------------------------
#define PICK_BIN()                                                             \
  {                                                                            \
    _Pragma("unroll")                                                          \
    for (int d = 1; d < 256; d <<= 1) {                                        \
      int v = (t + d < 256) ? hist[t + d] : 0;                                 \
      __syncthreads();                                                         \
      hist[t] += v;                                                            \
      __syncthreads();                                                         \
    }                                                                          \
    const int Sb = hist[t];                                                    \
    const int Sb1 = (t == 255) ? 0 : hist[t + 1];                              \
    if (Sb >= krem && Sb1 < krem) { sChosen = t; sKrem = krem - Sb1; }         \
    __syncthreads();                                                           \
  }

// ---------------------------------------------------------------------------
// Kernel 2: FUSED top-K select (topkL in LDS) + wave-per-row gather/norm
// (r13/r14, validated: absmax 0.0).
// ---------------------------------------------------------------------------
__global__ void selgather_kernel(const float* __restrict__ prob,
                                 const int* __restrict__ candCnt,
                                 const int* __restrict__ candIdx,
                                 const float* __restrict__ candVal,
                                 const float* __restrict__ zi,
                                 const float* __restrict__ zj,
                                 char* __restrict__ FT) {
  __shared__ float vals[MAXCAND];
  __shared__ int   idxs[MAXCAND];
  __shared__ int hist[256];
  __shared__ int pref[NPART + 1];
  __shared__ int cntL[NPART];
  __shared__ int topkL[KK];
  __shared__ int eqIdx[256];
  __shared__ int sChosen, sKrem, gtc, eqc, bad;
  const int c = blockIdx.x, t = threadIdx.x;

  if (t == 0) bad = 0;
  __syncthreads();
  if (t < NPART) {
    int cnt_p = candCnt[t * CC + c];
    cntL[t] = cnt_p;
    if (cnt_p > PCAP) bad = 1;
    int x = cnt_p;
#pragma unroll
    for (int d = 1; d < 64; d <<= 1) {
      int y = __shfl_up(x, d, 64);
      if (t >= d) x += y;
    }
    pref[t + 1] = x;
    if (t == 0) pref[0] = 0;
  }
  __syncthreads();
  const int total = pref[NPART];

  if (!bad && total >= KK && total <= MAXCAND) {
    for (int idx = t; idx < NPART * PCAP; idx += 256) {
      const int pt = idx >> 5, sl = idx & 31;
      if (sl < cntL[pt]) {
        const int o = pref[pt] + sl;
        vals[o] = candVal[(pt * CC + c) * PCAP + sl];
        idxs[o] = candIdx[(pt * CC + c) * PCAP + sl];
      }
    }
    __syncthreads();
    unsigned prefix = 0;
    int krem = KK;
    for (int pass = 0; pass < 4; ++pass) {
      const int shift = 24 - pass * 8;
      hist[t] = 0;
      __syncthreads();
      for (int j = t; j < total; j += 256) {
        unsigned u = __float_as_uint(vals[j]);
        bool match = (pass == 0) || ((u >> (shift + 8)) == (prefix >> (shift + 8)));
        if (match) atomicAdd(&hist[(u >> shift) & 255], 1);
      }
      __syncthreads();
      PICK_BIN()
      prefix |= ((unsigned)sChosen) << shift;
      krem = sKrem;
      __syncthreads();
    }
    const unsigned T = prefix;
    if (t == 0) { gtc = 0; eqc = 0; }
    __syncthreads();
    for (int j = t; j < total; j += 256) {
      unsigned u = __float_as_uint(vals[j]);
      if (u > T) {
        int pos = atomicAdd(&gtc, 1);
        topkL[pos] = idxs[j];
      } else if (u == T) {
        int e = atomicAdd(&eqc, 1);
        if (e < 256) eqIdx[e] = idxs[j];
      }
    }
    __syncthreads();
    if (t == 0) {
      int base = gtc;
      int ec = eqc < 256 ? eqc : 256;
      for (int j2 = 0; j2 < krem; ++j2) {
        int bi = -1, bv = 0x7fffffff;
        for (int q = 0; q < ec; ++q) {
          int v = eqIdx[q];
          if (v >= 0 && v < bv) { bv = v; bi = q; }
        }
        topkL[base + j2] = bv;
        eqIdx[bi] = -1;
      }
    }
  } else {
    unsigned prefix = 0;
    int krem = KK;
    for (int pass = 0; pass < 4; ++pass) {
      const int shift = 24 - pass * 8;
      hist[t] = 0;
      __syncthreads();
      for (int i = t; i < BB; i += 256) {
        unsigned u = __float_as_uint(prob[i * CC + c]);
        bool match = (pass == 0) || ((u >> (shift + 8)) == (prefix >> (shift + 8)));
        if (match) atomicAdd(&hist[(u >> shift) & 255], 1);
      }
      __syncthreads();
      PICK_BIN()
      prefix |= ((unsigned)sChosen) << shift;
      krem = sKrem;
      __syncthreads();
    }
    const unsigned T = prefix;
    if (t == 0) { gtc = 0; eqc = 0; }
    __syncthreads();
    for (int i = t; i < BB; i += 256) {
      unsigned u = __float_as_uint(prob[i * CC + c]);
      if (u > T) {
        int pos = atomicAdd(&gtc, 1);
        topkL[pos] = i;
      } else if (u == T) {
        int e = atomicAdd(&eqc, 1);
        if (e < 256) eqIdx[e] = i;
      }
    }
    __syncthreads();
    if (t == 0) {
      int base = gtc;
      int ec = eqc < 256 ? eqc : 256;
      for (int j = 0; j < krem; ++j) {
        int bi = -1, bv = 0x7fffffff;
        for (int q = 0; q < ec; ++q) {
          int v = eqIdx[q];
          if (v >= 0 && v < bv) { bv = v; bi = q; }
        }
        topkL[base + j] = bv;
        eqIdx[bi] = -1;
      }
    }
  }

  // ---- Phase 2: wave-per-row gather + normalize + tiled bf16 write ----
  __syncthreads();
  const int lane = t & 63, wv = t >> 6;
  for (int it = 0; it < 64; ++it) {
    const int p = wv * 64 + it;
    const int idx = topkL[p & (KK - 1)];
    const float* src = (p < KK ? zi : zj) + (size_t)idx * DD;
    float2 v = ((const float2*)src)[lane];
    float ss = fmaf(v.x, v.x, v.y * v.y);
#pragma unroll
    for (int m = 1; m < 64; m <<= 1) ss += __shfl_xor(ss, m, 64);
    const float scale = SQS / fmaxf(sqrtf(ss), 1e-8f);
    unsigned short ah = f2bf(v.x * scale), bh = f2bf(v.y * scale);
    unsigned hp = ((unsigned)bh << 16) | ah;
    const int gw = c * 256 + p;
    const int k2 = 2 * lane;
    const int kc = k2 >> 4;
    const int kk = k2 & 15;
    const size_t off = (size_t)(gw >> 5) * 8192 + (size_t)kc * 1024 +
                       (size_t)(((kk >> 3) * 32 + (gw & 31)) * 16 + (kk & 7) * 2);
    *(unsigned*)(FT + off) = hp;
  }
}

// ---------------------------------------------------------------------------
// Kernel 3: PANELIZED symmetric sim (r10/r12, validated). No cross-block sync.
// ---------------------------------------------------------------------------
__global__ __launch_bounds__(128, 2) void sim_sym_kernel(
    const char* __restrict__ F, float* __restrict__ part,
    float* __restrict__ ownArr, float* __restrict__ posArr) {
  __shared__ float colLds[2][1024];
  const int tid = threadIdx.x;
  const int lane = tid & 63, wave = tid >> 6;
  const int lh2 = lane >> 5;
  const size_t lo16 = (size_t)lane * 16;

  f32x16 Z = {};

#define LOADB(BUF, GIDX) {                                                     \
    _Pragma("unroll")                                                          \
    for (int kc = 0; kc < 8; ++kc)                                             \
      BUF[kc] = *(const bf16x8*)(F + (size_t)(GIDX) * 8192 + kc * 1024 + lo16);\
  }

  if (blockIdx.x < NBLK * NCHUNK) {
    const int I = blockIdx.x / NCHUNK, q = blockIdx.x - I * NCHUNK;
    const int J0 = I + q * CHT;
    if (J0 >= NBLK) return;
    const int nt = min(CHT, NBLK - J0);
    const int S = nt * 4;
    const int G0 = J0 * 4;
    const int Ga = I * 4 + wave * 2;

    bf16x8 A0[8], A1[8];
#pragma unroll
    for (int kc = 0; kc < 8; ++kc) {
      A0[kc] = *(const bf16x8*)(F + (size_t)Ga * 8192 + kc * 1024 + lo16);
      A1[kc] = *(const bf16x8*)(F + (size_t)(Ga + 1) * 8192 + kc * 1024 + lo16);
    }
    bf16x8 b0[8], b1[8];
    f32x16 aA0, aA1, aB0, aB1;
    float rAcc0[16], rAcc1[16];
#pragma unroll
    for (int r = 0; r < 16; ++r) { rAcc0[r] = 0.f; rAcc1[r] = 0.f; }
    float colv = 0.f;

#define PROC(AC0, AC1, BB_, AP0, AP1)                                          \
    AC0 = MFMA32(A0[0], BB_[0], Z); AC1 = MFMA32(A1[0], BB_[0], Z);            \
    _Pragma("unroll")                                                          \
    for (int kc = 1; kc < 8; ++kc) {                                           \
      AC0 = MFMA32(A0[kc], BB_[kc], AC0);                                      \
      AC1 = MFMA32(A1[kc], BB_[kc], AC1);                                      \
      const int r0 = 2 * (kc - 1), r1 = r0 + 1;                                \
      float e0 = __builtin_amdgcn_exp2f(AP0[r0]);                              \
      float e1 = __builtin_amdgcn_exp2f(AP0[r1]);                              \
      float e2 = __builtin_amdgcn_exp2f(AP1[r0]);                              \
      float e3 = __builtin_amdgcn_exp2f(AP1[r1]);                              \
      rAcc0[r0] += e0; rAcc0[r1] += e1; rAcc1[r0] += e2; rAcc1[r1] += e3;      \
      colv += (e0 + e1) + (e2 + e3);                                           \
    }                                                                          \
    { float e0 = __builtin_amdgcn_exp2f(AP0[14]);                              \
      float e1 = __builtin_amdgcn_exp2f(AP0[15]);                              \
      float e2 = __builtin_amdgcn_exp2f(AP1[14]);                              \
      float e3 = __builtin_amdgcn_exp2f(AP1[15]);                              \
      rAcc0[14] += e0; rAcc0[15] += e1; rAcc1[14] += e2; rAcc1[15] += e3;      \
      colv += (e0 + e1) + (e2 + e3); }

#define FINCOL(S_) {                                                           \
    float cv = colv + __shfl_xor(colv, 32, 64);                                \
    if (lane < 32) colLds[wave][(S_) * 32 + lane] = cv;                        \
    colv = 0.f; }

    LOADB(b0, G0)
    aA0 = MFMA32(A0[0], b0[0], Z); aA1 = MFMA32(A1[0], b0[0], Z);
#pragma unroll
    for (int kc = 1; kc < 8; ++kc) {
      aA0 = MFMA32(A0[kc], b0[kc], aA0);
      aA1 = MFMA32(A1[kc], b0[kc], aA1);
    }
    LOADB(b1, G0 + 1)

    int s = 1;
    for (; s + 1 < S; s += 2) {
      PROC(aB0, aB1, b1, aA0, aA1)
      FINCOL(s - 1)
      LOADB(b0, G0 + s + 1)
      PROC(aA0, aA1, b0, aB0, aB1)
      FINCOL(s)
      LOADB(b1, G0 + s + 2)
    }
    PROC(aB0, aB1, b1, aA0, aA1)
    FINCOL(S - 2)
#pragma unroll
    for (int r = 0; r < 16; ++r) {
      float e0 = __builtin_amdgcn_exp2f(aB0[r]);
      float e1 = __builtin_amdgcn_exp2f(aB1[r]);
      rAcc0[r] += e0; rAcc1[r] += e1;
      colv += e0 + e1;
    }
    FINCOL(S - 1)
#undef PROC
#undef FINCOL

    __syncthreads();
    for (int idx = tid; idx < S * 32; idx += 128) {
      const int J = J0 + (idx >> 7);
      if (J != I)
        part[(size_t)I * MM + J * 128 + (idx & 127)] = colLds[0][idx] + colLds[1][idx];
    }

#pragma unroll
    for (int m = 1; m < 32; m <<= 1)
#pragma unroll
      for (int r = 0; r < 16; ++r) {
        rAcc0[r] += __shfl_xor(rAcc0[r], m, 32);
        rAcc1[r] += __shfl_xor(rAcc1[r], m, 32);
      }
    if ((lane & 31) == 0) {
      const int rbase = I * 128 + wave * 64;
#pragma unroll
      for (int r = 0; r < 16; ++r) {
        const int rl = (r & 3) + 8 * (r >> 2) + 4 * lh2;
        part[(size_t)(NBLK + q) * MM + rbase + rl] = rAcc0[r];
        part[(size_t)(NBLK + q) * MM + rbase + 32 + rl] = rAcc1[r];
      }
    }
  } else {
    // ================= own/pos path (r9, validated) =================
    const int bid2 = blockIdx.x - NBLK * NCHUNK;
    const int c = bid2 >> 1, q2 = bid2 & 1;
    const int Ga = c * 8 + q2 * 4 + wave * 2;
    const int c8 = c * 8;

    bf16x8 A0[8], A1[8];
#pragma unroll
    for (int kc = 0; kc < 8; ++kc) {
      A0[kc] = *(const bf16x8*)(F + (size_t)Ga * 8192 + kc * 1024 + lo16);
      A1[kc] = *(const bf16x8*)(F + (size_t)(Ga + 1) * 8192 + kc * 1024 + lo16);
    }
    bf16x8 b0[8], b1[8];
    float rAcc0[16], rAcc1[16];
#pragma unroll
    for (int r = 0; r < 16; ++r) { rAcc0[r] = 0.f; rAcc1[r] = 0.f; }

#define OWNTILE(BB_) {                                                         \
    f32x16 a0 = MFMA32(A0[0], BB_[0], Z), a1 = MFMA32(A1[0], BB_[0], Z);       \
    _Pragma("unroll")                                                          \
    for (int kc = 1; kc < 8; ++kc) {                                           \
      a0 = MFMA32(A0[kc], BB_[kc], a0); a1 = MFMA32(A1[kc], BB_[kc], a1); }    \
    _Pragma("unroll")                                                          \
    for (int r = 0; r < 16; ++r) {                                             \
      rAcc0[r] += __builtin_amdgcn_exp2f(a0[r]);                               \
      rAcc1[r] += __builtin_amdgcn_exp2f(a1[r]); } }

#define REDUCEW(DST) {                                                         \
    float t0[16], t1[16];                                                      \
    _Pragma("unroll")                                                          \
    for (int r = 0; r < 16; ++r) { t0[r] = rAcc0[r]; t1[r] = rAcc1[r]; }       \
    _Pragma("unroll")                                                          \
    for (int m = 1; m < 32; m <<= 1)                                           \
      _Pragma("unroll")                                                        \
      for (int r = 0; r < 16; ++r) {                                           \
        t0[r] += __shfl_xor(t0[r], m, 32);                                     \
        t1[r] += __shfl_xor(t1[r], m, 32); }                                   \
    if ((lane & 31) == 0) {                                                    \
      const int rbase = c * 256 + q2 * 128 + wave * 64;                        \
      _Pragma("unroll")                                                        \
      for (int r = 0; r < 16; ++r) {                                           \
        const int rl = (r & 3) + 8 * (r >> 2) + 4 * lh2;                       \
        DST[rbase + rl] = t0[r];                                               \
        DST[rbase + 32 + rl] = t1[r]; } } }

    LOADB(b0, c8 + 0)
    LOADB(b1, c8 + 1)  OWNTILE(b0)
    LOADB(b0, c8 + 2)  OWNTILE(b1)
    LOADB(b1, c8 + 3)  OWNTILE(b0)
    LOADB(b0, c8 + 4)  OWNTILE(b1)
    REDUCEW(posArr)
    LOADB(b1, c8 + 5)  OWNTILE(b0)
    LOADB(b0, c8 + 6)  OWNTILE(b1)
    LOADB(b1, c8 + 7)  OWNTILE(b0)
    OWNTILE(b1)
    REDUCEW(ownArr)
#undef OWNTILE
#undef REDUCEW
  }
#undef LOADB
}

// ---------------------------------------------------------------------------
// Kernel 4: per-row loss + block reduction + last-block mean via ticket
// (r12, validated at 109us; ticket is only among these 50 blocks).
// ---------------------------------------------------------------------------
__global__ void finalize_kernel(const float* __restrict__ part,
                                const float* __restrict__ ownArr,
                                const float* __restrict__ posArr,
                                float* __restrict__ partial,
                                int* __restrict__ ticket,
                                float* __restrict__ out) {
  __shared__ float red[4];
  const int t = threadIdx.x;
  const int p = blockIdx.x * 256 + t;
  const int pb = p >> 7;
  float a = 0.f;
  for (int b = 0; b < pb; ++b) a += part[(size_t)b * MM + p];
  const int qmax = (NBLK - 1 - pb) >> 3;
  for (int q = 0; q <= qmax; ++q) a += part[(size_t)(NBLK + q) * MM + p];
  float rl = logf(a - ownArr[p]) - logf(posArr[p]);
#pragma unroll
  for (int m = 1; m < 64; m <<= 1) rl += __shfl_xor(rl, m, 64);
  if ((t & 63) == 0) red[t >> 6] = rl;
  __syncthreads();
  if (t == 0) {
    const float bsum = red[0] + red[1] + red[2] + red[3];
    __hip_atomic_store(&partial[blockIdx.x], bsum, __ATOMIC_RELEASE,
                       __HIP_MEMORY_SCOPE_AGENT);
    const int old = __hip_atomic_fetch_add(ticket, 1, __ATOMIC_ACQ_REL,
                                           __HIP_MEMORY_SCOPE_AGENT);
    if (old == (MM / 256) - 1) {          // last block: deterministic sum
      float s = 0.f;
      for (int i = 0; i < MM / 256; ++i)
        s += __hip_atomic_load(&partial[i], __ATOMIC_ACQUIRE,
                               __HIP_MEMORY_SCOPE_AGENT);
      out[0] = s * (1.0f / MM);
    }
  }
}

extern "C" void kernel_launch(void* const* d_in, const int* in_sizes, int n_in,
                              void* d_out, int out_size, void* d_ws, size_t ws_size,
                              hipStream_t stream) {
  const float* prob = (const float*)d_in[0];
  const float* zi   = (const float*)d_in[1];
  const float* zj   = (const float*)d_in[2];
  float* out = (float*)d_out;

  char* ws = (char*)d_ws;
  char*  FT       = ws;                                  // 3,276,800 B
  float* part     = (float*)(ws + 3276800);              // 113*12800*4 = 5,785,600 B
  // cand buffers alias the (not-yet-live) part region: dead before sim writes.
  int*   candCnt  = (int*)  (ws + 3276800);              //    12,800 B
  int*   candIdx  = (int*)  (ws + 3276800 + 16384);      //   409,600 B
  float* candVal  = (float*)(ws + 3276800 + 430080);     //   409,600 B
  float* ownArr   = (float*)(ws + 9062400);              //    51,200 B
  float* posArr   = (float*)(ws + 9113600);              //    51,200 B
  float* partial  = (float*)(ws + 9164800);              //       256 B
  int*   ticket   = (int*)  (ws + 9165056);              //         4 B

  cand_kernel     <<<NPART, 256, 0, stream>>>(prob, candCnt, candIdx, candVal, ticket);
  selgather_kernel<<<CC, 256, 0, stream>>>(prob, candCnt, candIdx, candVal, zi, zj, FT);
  sim_sym_kernel  <<<NBLK * NCHUNK + 2 * CC, 128, 0, stream>>>(FT, part, ownArr, posArr);
  finalize_kernel <<<MM / 256, 256, 0, stream>>>(part, ownArr, posArr, partial, ticket, out);
}

// Round 16
// 109.759 us; speedup vs baseline: 2.3172x; 1.2702x over previous
//
#include <hip/hip_runtime.h>
#include <math.h>

#define BB 16384      // B
#define CC 50         // clusters
#define KK 128        // top-K
#define DD 128        // feature dim
#define MM 12800      // CC*2*KK rows of F
#define NBLK 100      // 128-row blocks of F
#define NCHUNK 13     // J-chunks per row (chunk = 8 tiles)
#define CHT 8         // tiles per chunk
#define MAXCAND 2048
#define TCAND 0.97f
#define NPART 64      // candidate partitions (256 rows each)
#define RPP 256       // rows per partition
#define PCAP 32       // per (partition,cluster) capacity; expected ~7.7
#define GSUB 4        // sub-blocks per cluster in selgather (redundant select)
// F rows pre-scaled by SQS = sqrt(2/ln2): dot(F,F) = sim*2/ln2 -> exp2 direct.
// Single bf16 product (validated r8-r15: absmax 0.0 vs reference).
#define SQS 1.6986436f

// Tiled F layout: for each 32-row group G (400 groups), each kc (16-K chunk,
// 8 chunks), 64 granules of 16B lane-ordered for mfma_32x32x16_bf16 operands.
// One fragment load = contiguous 1KB wave load at G*8192 + kc*1024 + lane*16.
//
// LESSON (r13/r14): intra-kernel producer->consumer sync costs a per-block
// device-fence L2-writeback tax (~150us for 1400 blocks on 8 XCDs) — keep
// pipeline stages as separate graph nodes.
// LESSON (r11/r15): a 50-block gather phase is latency-starved (55us). Fix:
// redundant per-cluster select across GSUB blocks (deterministic scan-based
// compaction, NO atomic ordering) so the gather gets GSUB x the parallelism.

typedef __bf16 bf16x8 __attribute__((ext_vector_type(8)));
typedef float f32x16 __attribute__((ext_vector_type(16)));

#define MFMA32(a, b, c) __builtin_amdgcn_mfma_f32_32x32x16_bf16(a, b, c, 0, 0, 0)

__device__ inline unsigned short f2bf(float x) {
  unsigned u = __float_as_uint(x);
  unsigned r = (u + 0x7fffu + ((u >> 16) & 1u)) >> 16;
  return (unsigned short)r;
}

// ---------------------------------------------------------------------------
// Kernel 1: candidate collection, zero global atomics (r9, validated).
// Zeroes the finalize ticket for this launch.
// ---------------------------------------------------------------------------
__global__ void cand_kernel(const float* __restrict__ prob, int* __restrict__ candCnt,
                            int* __restrict__ candIdx, float* __restrict__ candVal,
                            int* __restrict__ ticket) {
  __shared__ int lcnt[CC];
  const int b = blockIdx.x, t = threadIdx.x;
  if (b == 0 && t == 0) *ticket = 0;
  if (t < CC) lcnt[t] = 0;
  __syncthreads();
  const int base = b * RPP * CC;
  for (int i = t; i < RPP * CC; i += 256) {
    const float v = prob[base + i];
    if (v >= TCAND) {
      const int r = i / CC, c = i - r * CC;
      const int slot = atomicAdd(&lcnt[c], 1);
      if (slot < PCAP) {
        candIdx[(b * CC + c) * PCAP + slot] = b * RPP + r;
        candVal[(b * CC + c) * PCAP + slot] = v;
      }
    }
  }
  __syncthreads();
  if (t < CC) candCnt[b * CC + t] = lcnt[t];
}

// ---------------------------------------------------------------------------
// PARALLEL bin selection (r12, validated): suffix-sum ladder + crossing pick.
// Deterministic: integer histogram sums + ladder have no ordering dependence.
// ---------------------------------------------------------------------------
#define PICK_BIN()                                                             \
  {                                                                            \
    _Pragma("unroll")                                                          \
    for (int d = 1; d < 256; d <<= 1) {                                        \
      int v = (t + d < 256) ? hist[t + d] : 0;                                 \
      __syncthreads();                                                         \
      hist[t] += v;                                                            \
      __syncthreads();                                                         \
    }                                                                          \
    const int Sb = hist[t];                                                    \
    const int Sb1 = (t == 255) ? 0 : hist[t + 1];                              \
    if (Sb >= krem && Sb1 < krem) { sChosen = t; sKrem = krem - Sb1; }         \
    __syncthreads();                                                           \
  }

// Deterministic compaction: chunked array-order scan of (gt,eq) flags packed
// 16:16 into one inclusive-scan ladder; gt elements -> topkL[0..gtCount),
// eq elements -> eqIdx[] in array order; thread 0 picks krem smallest-index
// equals into topkL[gtCount..KK). No atomics -> bit-identical across blocks.
#define COMPACT_DET(TOTAL, GETU, GETI)                                         \
  {                                                                            \
    const int chunk = ((TOTAL) + 255) >> 8;                                    \
    const int j0 = t * chunk;                                                  \
    const int j1 = (j0 + chunk < (TOTAL)) ? j0 + chunk : (TOTAL);              \
    int myGt = 0, myEq = 0;                                                    \
    for (int j = j0; j < j1; ++j) {                                            \
      unsigned u = (GETU);                                                     \
      myGt += (u > T) ? 1 : 0; myEq += (u == T) ? 1 : 0;                       \
    }                                                                          \
    hist[t] = (myGt << 16) | myEq;                                             \
    __syncthreads();                                                           \
    _Pragma("unroll")                                                          \
    for (int d = 1; d < 256; d <<= 1) {                                        \
      int v = (t >= d) ? hist[t - d] : 0;                                      \
      __syncthreads();                                                         \
      hist[t] += v;                                                            \
      __syncthreads();                                                         \
    }                                                                          \
    const int incl = hist[t];                                                  \
    const int gtCount = (hist[255] >> 16) & 0xffff;                            \
    const int eqTotal = hist[255] & 0xffff;                                    \
    int pg = ((incl >> 16) & 0xffff) - myGt;                                   \
    int pe = (incl & 0xffff) - myEq;                                           \
    for (int j = j0; j < j1; ++j) {                                            \
      unsigned u = (GETU);                                                     \
      if (u > T) topkL[pg++] = (GETI);                                         \
      else if (u == T) { if (pe < 256) eqIdx[pe] = (GETI); pe++; }             \
    }                                                                          \
    __syncthreads();                                                           \
    if (t == 0) {                                                              \
      int krem2 = KK - gtCount;                                                \
      int ec = eqTotal < 256 ? eqTotal : 256;                                  \
      for (int j2 = 0; j2 < krem2; ++j2) {                                     \
        int bi = -1, bv = 0x7fffffff;                                          \
        for (int q = 0; q < ec; ++q) {                                         \
          int v = eqIdx[q];                                                    \
          if (v >= 0 && v < bv) { bv = v; bi = q; }                            \
        }                                                                      \
        topkL[gtCount + j2] = bv;                                              \
        eqIdx[bi] = -1;                                                        \
      }                                                                        \
    }                                                                          \
  }

// ---------------------------------------------------------------------------
// Kernel 2: FUSED top-K select + gather/norm, GSUB blocks per cluster.
// All GSUB blocks of a cluster compute the IDENTICAL topkL (deterministic
// select: global-memory inputs + scan-based compaction), then each gathers
// its own 64-row slice -> 200 blocks of parallelism for the gather phase.
// ---------------------------------------------------------------------------
__global__ void selgather_kernel(const float* __restrict__ prob,
                                 const int* __restrict__ candCnt,
                                 const int* __restrict__ candIdx,
                                 const float* __restrict__ candVal,
                                 const float* __restrict__ zi,
                                 const float* __restrict__ zj,
                                 char* __restrict__ FT) {
  __shared__ float vals[MAXCAND];
  __shared__ int   idxs[MAXCAND];
  __shared__ int hist[256];
  __shared__ int pref[NPART + 1];
  __shared__ int cntL[NPART];
  __shared__ int topkL[KK];
  __shared__ int eqIdx[256];
  __shared__ int sChosen, sKrem, bad;
  const int c = blockIdx.x / GSUB, g = blockIdx.x - c * GSUB;
  const int t = threadIdx.x;

  if (t == 0) bad = 0;
  __syncthreads();
  if (t < NPART) {
    int cnt_p = candCnt[t * CC + c];
    cntL[t] = cnt_p;
    if (cnt_p > PCAP) bad = 1;
    int x = cnt_p;
#pragma unroll
    for (int d = 1; d < 64; d <<= 1) {
      int y = __shfl_up(x, d, 64);
      if (t >= d) x += y;
    }
    pref[t + 1] = x;
    if (t == 0) pref[0] = 0;
  }
  __syncthreads();
  const int total = pref[NPART];

  if (!bad && total >= KK && total <= MAXCAND) {
    // ---- coalesced candidate gather into LDS (deterministic layout) ----
    for (int idx = t; idx < NPART * PCAP; idx += 256) {
      const int pt = idx >> 5, sl = idx & 31;
      if (sl < cntL[pt]) {
        const int o = pref[pt] + sl;
        vals[o] = candVal[(pt * CC + c) * PCAP + sl];
        idxs[o] = candIdx[(pt * CC + c) * PCAP + sl];
      }
    }
    __syncthreads();
    unsigned prefix = 0;
    int krem = KK;
    for (int pass = 0; pass < 4; ++pass) {
      const int shift = 24 - pass * 8;
      hist[t] = 0;
      __syncthreads();
      for (int j = t; j < total; j += 256) {
        unsigned u = __float_as_uint(vals[j]);
        bool match = (pass == 0) || ((u >> (shift + 8)) == (prefix >> (shift + 8)));
        if (match) atomicAdd(&hist[(u >> shift) & 255], 1);
      }
      __syncthreads();
      PICK_BIN()
      prefix |= ((unsigned)sChosen) << shift;
      krem = sKrem;
      __syncthreads();
    }
    const unsigned T = prefix;
    COMPACT_DET(total, __float_as_uint(vals[j]), idxs[j])
  } else {
    // ---- exact fallback: full column radix select (deterministic) ----
    unsigned prefix = 0;
    int krem = KK;
    for (int pass = 0; pass < 4; ++pass) {
      const int shift = 24 - pass * 8;
      hist[t] = 0;
      __syncthreads();
      for (int i = t; i < BB; i += 256) {
        unsigned u = __float_as_uint(prob[i * CC + c]);
        bool match = (pass == 0) || ((u >> (shift + 8)) == (prefix >> (shift + 8)));
        if (match) atomicAdd(&hist[(u >> shift) & 255], 1);
      }
      __syncthreads();
      PICK_BIN()
      prefix |= ((unsigned)sChosen) << shift;
      krem = sKrem;
      __syncthreads();
    }
    const unsigned T = prefix;
    COMPACT_DET(BB, __float_as_uint(prob[(size_t)j * CC + c]), j)
  }

  // ---- Phase 2: gather rows [g*64, g*64+64); wave-per-row, 16 rows/wave ----
  __syncthreads();
  const int lane = t & 63, wv = t >> 6;
#pragma unroll 4
  for (int it = 0; it < 16; ++it) {
    const int p = g * 64 + wv * 16 + it;
    const int idx = topkL[p & (KK - 1)];
    const float* src = (p < KK ? zi : zj) + (size_t)idx * DD;
    float2 v = ((const float2*)src)[lane];
    float ss = fmaf(v.x, v.x, v.y * v.y);
#pragma unroll
    for (int m = 1; m < 64; m <<= 1) ss += __shfl_xor(ss, m, 64);
    const float scale = SQS / fmaxf(sqrtf(ss), 1e-8f);
    unsigned short ah = f2bf(v.x * scale), bh = f2bf(v.y * scale);
    unsigned hp = ((unsigned)bh << 16) | ah;
    const int gw = c * 256 + p;
    const int k2 = 2 * lane;
    const int kc = k2 >> 4;
    const int kk = k2 & 15;
    const size_t off = (size_t)(gw >> 5) * 8192 + (size_t)kc * 1024 +
                       (size_t)(((kk >> 3) * 32 + (gw & 31)) * 16 + (kk & 7) * 2);
    *(unsigned*)(FT + off) = hp;
  }
}

// ---------------------------------------------------------------------------
// Kernel 3: PANELIZED symmetric sim (r10/r12, validated). No cross-block sync.
// ---------------------------------------------------------------------------
__global__ __launch_bounds__(128, 2) void sim_sym_kernel(
    const char* __restrict__ F, float* __restrict__ part,
    float* __restrict__ ownArr, float* __restrict__ posArr) {
  __shared__ float colLds[2][1024];
  const int tid = threadIdx.x;
  const int lane = tid & 63, wave = tid >> 6;
  const int lh2 = lane >> 5;
  const size_t lo16 = (size_t)lane * 16;

  f32x16 Z = {};

#define LOADB(BUF, GIDX) {                                                     \
    _Pragma("unroll")                                                          \
    for (int kc = 0; kc < 8; ++kc)                                             \
      BUF[kc] = *(const bf16x8*)(F + (size_t)(GIDX) * 8192 + kc * 1024 + lo16);\
  }

  if (blockIdx.x < NBLK * NCHUNK) {
    const int I = blockIdx.x / NCHUNK, q = blockIdx.x - I * NCHUNK;
    const int J0 = I + q * CHT;
    if (J0 >= NBLK) return;
    const int nt = min(CHT, NBLK - J0);
    const int S = nt * 4;
    const int G0 = J0 * 4;
    const int Ga = I * 4 + wave * 2;

    bf16x8 A0[8], A1[8];
#pragma unroll
    for (int kc = 0; kc < 8; ++kc) {
      A0[kc] = *(const bf16x8*)(F + (size_t)Ga * 8192 + kc * 1024 + lo16);
      A1[kc] = *(const bf16x8*)(F + (size_t)(Ga + 1) * 8192 + kc * 1024 + lo16);
    }
    bf16x8 b0[8], b1[8];
    f32x16 aA0, aA1, aB0, aB1;
    float rAcc0[16], rAcc1[16];
#pragma unroll
    for (int r = 0; r < 16; ++r) { rAcc0[r] = 0.f; rAcc1[r] = 0.f; }
    float colv = 0.f;

#define PROC(AC0, AC1, BB_, AP0, AP1)                                          \
    AC0 = MFMA32(A0[0], BB_[0], Z); AC1 = MFMA32(A1[0], BB_[0], Z);            \
    _Pragma("unroll")                                                          \
    for (int kc = 1; kc < 8; ++kc) {                                           \
      AC0 = MFMA32(A0[kc], BB_[kc], AC0);                                      \
      AC1 = MFMA32(A1[kc], BB_[kc], AC1);                                      \
      const int r0 = 2 * (kc - 1), r1 = r0 + 1;                                \
      float e0 = __builtin_amdgcn_exp2f(AP0[r0]);                              \
      float e1 = __builtin_amdgcn_exp2f(AP0[r1]);                              \
      float e2 = __builtin_amdgcn_exp2f(AP1[r0]);                              \
      float e3 = __builtin_amdgcn_exp2f(AP1[r1]);                              \
      rAcc0[r0] += e0; rAcc0[r1] += e1; rAcc1[r0] += e2; rAcc1[r1] += e3;      \
      colv += (e0 + e1) + (e2 + e3);                                           \
    }                                                                          \
    { float e0 = __builtin_amdgcn_exp2f(AP0[14]);                              \
      float e1 = __builtin_amdgcn_exp2f(AP0[15]);                              \
      float e2 = __builtin_amdgcn_exp2f(AP1[14]);                              \
      float e3 = __builtin_amdgcn_exp2f(AP1[15]);                              \
      rAcc0[14] += e0; rAcc0[15] += e1; rAcc1[14] += e2; rAcc1[15] += e3;      \
      colv += (e0 + e1) + (e2 + e3); }

#define FINCOL(S_) {                                                           \
    float cv = colv + __shfl_xor(colv, 32, 64);                                \
    if (lane < 32) colLds[wave][(S_) * 32 + lane] = cv;                        \
    colv = 0.f; }

    LOADB(b0, G0)
    aA0 = MFMA32(A0[0], b0[0], Z); aA1 = MFMA32(A1[0], b0[0], Z);
#pragma unroll
    for (int kc = 1; kc < 8; ++kc) {
      aA0 = MFMA32(A0[kc], b0[kc], aA0);
      aA1 = MFMA32(A1[kc], b0[kc], aA1);
    }
    LOADB(b1, G0 + 1)

    int s = 1;
    for (; s + 1 < S; s += 2) {
      PROC(aB0, aB1, b1, aA0, aA1)
      FINCOL(s - 1)
      LOADB(b0, G0 + s + 1)
      PROC(aA0, aA1, b0, aB0, aB1)
      FINCOL(s)
      LOADB(b1, G0 + s + 2)
    }
    PROC(aB0, aB1, b1, aA0, aA1)
    FINCOL(S - 2)
#pragma unroll
    for (int r = 0; r < 16; ++r) {
      float e0 = __builtin_amdgcn_exp2f(aB0[r]);
      float e1 = __builtin_amdgcn_exp2f(aB1[r]);
      rAcc0[r] += e0; rAcc1[r] += e1;
      colv += e0 + e1;
    }
    FINCOL(S - 1)
#undef PROC
#undef FINCOL

    __syncthreads();
    for (int idx = tid; idx < S * 32; idx += 128) {
      const int J = J0 + (idx >> 7);
      if (J != I)
        part[(size_t)I * MM + J * 128 + (idx & 127)] = colLds[0][idx] + colLds[1][idx];
    }

#pragma unroll
    for (int m = 1; m < 32; m <<= 1)
#pragma unroll
      for (int r = 0; r < 16; ++r) {
        rAcc0[r] += __shfl_xor(rAcc0[r], m, 32);
        rAcc1[r] += __shfl_xor(rAcc1[r], m, 32);
      }
    if ((lane & 31) == 0) {
      const int rbase = I * 128 + wave * 64;
#pragma unroll
      for (int r = 0; r < 16; ++r) {
        const int rl = (r & 3) + 8 * (r >> 2) + 4 * lh2;
        part[(size_t)(NBLK + q) * MM + rbase + rl] = rAcc0[r];
        part[(size_t)(NBLK + q) * MM + rbase + 32 + rl] = rAcc1[r];
      }
    }
  } else {
    // ================= own/pos path (r9, validated) =================
    const int bid2 = blockIdx.x - NBLK * NCHUNK;
    const int c = bid2 >> 1, q2 = bid2 & 1;
    const int Ga = c * 8 + q2 * 4 + wave * 2;
    const int c8 = c * 8;

    bf16x8 A0[8], A1[8];
#pragma unroll
    for (int kc = 0; kc < 8; ++kc) {
      A0[kc] = *(const bf16x8*)(F + (size_t)Ga * 8192 + kc * 1024 + lo16);
      A1[kc] = *(const bf16x8*)(F + (size_t)(Ga + 1) * 8192 + kc * 1024 + lo16);
    }
    bf16x8 b0[8], b1[8];
    float rAcc0[16], rAcc1[16];
#pragma unroll
    for (int r = 0; r < 16; ++r) { rAcc0[r] = 0.f; rAcc1[r] = 0.f; }

#define OWNTILE(BB_) {                                                         \
    f32x16 a0 = MFMA32(A0[0], BB_[0], Z), a1 = MFMA32(A1[0], BB_[0], Z);       \
    _Pragma("unroll")                                                          \
    for (int kc = 1; kc < 8; ++kc) {                                           \
      a0 = MFMA32(A0[kc], BB_[kc], a0); a1 = MFMA32(A1[kc], BB_[kc], a1); }    \
    _Pragma("unroll")                                                          \
    for (int r = 0; r < 16; ++r) {                                             \
      rAcc0[r] += __builtin_amdgcn_exp2f(a0[r]);                               \
      rAcc1[r] += __builtin_amdgcn_exp2f(a1[r]); } }

#define REDUCEW(DST) {                                                         \
    float t0[16], t1[16];                                                      \
    _Pragma("unroll")                                                          \
    for (int r = 0; r < 16; ++r) { t0[r] = rAcc0[r]; t1[r] = rAcc1[r]; }       \
    _Pragma("unroll")                                                          \
    for (int m = 1; m < 32; m <<= 1)                                           \
      _Pragma("unroll")                                                        \
      for (int r = 0; r < 16; ++r) {                                           \
        t0[r] += __shfl_xor(t0[r], m, 32);                                     \
        t1[r] += __shfl_xor(t1[r], m, 32); }                                   \
    if ((lane & 31) == 0) {                                                    \
      const int rbase = c * 256 + q2 * 128 + wave * 64;                        \
      _Pragma("unroll")                                                        \
      for (int r = 0; r < 16; ++r) {                                           \
        const int rl = (r & 3) + 8 * (r >> 2) + 4 * lh2;                       \
        DST[rbase + rl] = t0[r];                                               \
        DST[rbase + 32 + rl] = t1[r]; } } }

    LOADB(b0, c8 + 0)
    LOADB(b1, c8 + 1)  OWNTILE(b0)
    LOADB(b0, c8 + 2)  OWNTILE(b1)
    LOADB(b1, c8 + 3)  OWNTILE(b0)
    LOADB(b0, c8 + 4)  OWNTILE(b1)
    REDUCEW(posArr)
    LOADB(b1, c8 + 5)  OWNTILE(b0)
    LOADB(b0, c8 + 6)  OWNTILE(b1)
    LOADB(b1, c8 + 7)  OWNTILE(b0)
    OWNTILE(b1)
    REDUCEW(ownArr)
#undef OWNTILE
#undef REDUCEW
  }
#undef LOADB
}

// ---------------------------------------------------------------------------
// Kernel 4: per-row loss + block reduction + last-block mean via ticket
// (r12, validated at 109us; ticket is only among these 50 blocks).
// ---------------------------------------------------------------------------
__global__ void finalize_kernel(const float* __restrict__ part,
                                const float* __restrict__ ownArr,
                                const float* __restrict__ posArr,
                                float* __restrict__ partial,
                                int* __restrict__ ticket,
                                float* __restrict__ out) {
  __shared__ float red[4];
  const int t = threadIdx.x;
  const int p = blockIdx.x * 256 + t;
  const int pb = p >> 7;
  float a = 0.f;
  for (int b = 0; b < pb; ++b) a += part[(size_t)b * MM + p];
  const int qmax = (NBLK - 1 - pb) >> 3;
  for (int q = 0; q <= qmax; ++q) a += part[(size_t)(NBLK + q) * MM + p];
  float rl = logf(a - ownArr[p]) - logf(posArr[p]);
#pragma unroll
  for (int m = 1; m < 64; m <<= 1) rl += __shfl_xor(rl, m, 64);
  if ((t & 63) == 0) red[t >> 6] = rl;
  __syncthreads();
  if (t == 0) {
    const float bsum = red[0] + red[1] + red[2] + red[3];
    __hip_atomic_store(&partial[blockIdx.x], bsum, __ATOMIC_RELEASE,
                       __HIP_MEMORY_SCOPE_AGENT);
    const int old = __hip_atomic_fetch_add(ticket, 1, __ATOMIC_ACQ_REL,
                                           __HIP_MEMORY_SCOPE_AGENT);
    if (old == (MM / 256) - 1) {          // last block: deterministic sum
      float s = 0.f;
      for (int i = 0; i < MM / 256; ++i)
        s += __hip_atomic_load(&partial[i], __ATOMIC_ACQUIRE,
                               __HIP_MEMORY_SCOPE_AGENT);
      out[0] = s * (1.0f / MM);
    }
  }
}

extern "C" void kernel_launch(void* const* d_in, const int* in_sizes, int n_in,
                              void* d_out, int out_size, void* d_ws, size_t ws_size,
                              hipStream_t stream) {
  const float* prob = (const float*)d_in[0];
  const float* zi   = (const float*)d_in[1];
  const float* zj   = (const float*)d_in[2];
  float* out = (float*)d_out;

  char* ws = (char*)d_ws;
  char*  FT       = ws;                                  // 3,276,800 B
  float* part     = (float*)(ws + 3276800);              // 113*12800*4 = 5,785,600 B
  // cand buffers alias the (not-yet-live) part region: dead before sim writes.
  int*   candCnt  = (int*)  (ws + 3276800);              //    12,800 B
  int*   candIdx  = (int*)  (ws + 3276800 + 16384);      //   409,600 B
  float* candVal  = (float*)(ws + 3276800 + 430080);     //   409,600 B
  float* ownArr   = (float*)(ws + 9062400);              //    51,200 B
  float* posArr   = (float*)(ws + 9113600);              //    51,200 B
  float* partial  = (float*)(ws + 9164800);              //       256 B
  int*   ticket   = (int*)  (ws + 9165056);              //         4 B

  cand_kernel     <<<NPART, 256, 0, stream>>>(prob, candCnt, candIdx, candVal, ticket);
  selgather_kernel<<<CC * GSUB, 256, 0, stream>>>(prob, candCnt, candIdx, candVal, zi, zj, FT);
  sim_sym_kernel  <<<NBLK * NCHUNK + 2 * CC, 128, 0, stream>>>(FT, part, ownArr, posArr);
  finalize_kernel <<<MM / 256, 256, 0, stream>>>(part, ownArr, posArr, partial, ticket, out);
}